// Round 10
// baseline (75.379 us; speedup 1.0000x reference)
//
#include <hip/hip_runtime.h>
#include <math.h>

#define DIM 128
#define P_POS 3
#define N_NEG 63
#define SCALE 16.0f

typedef float floatx2 __attribute__((ext_vector_type(2)));

#if defined(__has_builtin)
#if __has_builtin(__builtin_elementwise_fma)
#define HAVE_EFMA 1
#endif
#endif

__device__ __forceinline__ floatx2 pkfma(floatx2 a, floatx2 b, floatx2 c) {
#ifdef HAVE_EFMA
    return __builtin_elementwise_fma(a, b, c);
#else
    floatx2 r;
    r.x = fmaf(a.x, b.x, c.x);
    r.y = fmaf(a.y, b.y, c.y);
    return r;
#endif
}

__device__ __forceinline__ float wave_reduce_sum(float v) {
#pragma unroll
    for (int off = 32; off > 0; off >>= 1) v += __shfl_xor(v, off, 64);
    return v;
}
__device__ __forceinline__ float g16_reduce(float v) {
#pragma unroll
    for (int off = 8; off > 0; off >>= 1) v += __shfl_xor(v, off, 64);
    return v;
}
__device__ __forceinline__ float g32_reduce(float v) {
#pragma unroll
    for (int off = 16; off > 0; off >>= 1) v += __shfl_xor(v, off, 64);
    return v;
}

// Normalize each ids_fut row, scale by 16, pack to fp8 e4m3 (round-3 proven).
__global__ __launch_bounds__(256) void prep_fp8_kernel(const float* __restrict__ fut,
                                                       unsigned* __restrict__ futq,
                                                       int nrows) {
    int half = threadIdx.x >> 5;
    int l = threadIdx.x & 31;
    int row = blockIdx.x * 8 + half;
    if (row >= nrows) return;
    float4 x = *reinterpret_cast<const float4*>(fut + (size_t)row * DIM + l * 4);
    float ss = x.x * x.x;
    ss = fmaf(x.y, x.y, ss);
    ss = fmaf(x.z, x.z, ss);
    ss = fmaf(x.w, x.w, ss);
    ss = g32_reduce(ss);
    float r = (ss > 0.f) ? rsqrtf(ss) * SCALE : 0.f;
    int w = __builtin_amdgcn_cvt_pk_fp8_f32(x.x * r, x.y * r, 0, false);
    w = __builtin_amdgcn_cvt_pk_fp8_f32(x.z * r, x.w * r, w, true);
    futq[(size_t)row * 32 + l] = (unsigned)w;
}

// One wave per anchor; 4 groups x 16 lanes (round-6 proven structure).
// Final reduction fused: ONE plain device-scope atomicAdd per block into
// d_out (zeroed by a 4-byte hipMemsetAsync). No __threadfence / acq-rel
// (round-5 lesson: explicit fence semantics force per-XCD L2
// writeback/invalidate -> 7x regression; a lone atomicAdd does not).
__global__ __launch_bounds__(256) void idloss_fp8a_kernel(
    const float* __restrict__ hist, const int* __restrict__ anchor_idx,
    const int* __restrict__ pos_idx, const int* __restrict__ neg_idx,
    const uint2* __restrict__ futq, float* __restrict__ out) {
    __shared__ float smem[4];
    const int wave = threadIdx.x >> 6;
    const int lane = threadIdx.x & 63;
    const int m = __builtin_amdgcn_readfirstlane(blockIdx.x * 4 + wave);
    const int g = lane >> 4;
    const int t = lane & 15;

    // per-lane coalesced neg-index load (broadcast via shfl below)
    int nidx = (lane < N_NEG) ? neg_idx[m * N_NEG + lane] : 0;

    // wave-uniform scalar loads (SMEM pipe, off the VALU)
    const int aidx = anchor_idx[m];
    const int p0 = pos_idx[m * P_POS + 0];
    const int p1 = pos_idx[m * P_POS + 1];
    const int p2 = pos_idx[m * P_POS + 2];
    int pidx = (g == 1) ? p1 : (g == 2) ? p2 : p0;

    // anchor row: elements [8t, 8t+8), replicated across the 4 groups
    const float4* ap =
        reinterpret_cast<const float4*>(hist + (size_t)aidx * DIM + t * 8);
    float4 a0 = ap[0], a1 = ap[1];
    float ss = a0.x * a0.x;
    ss = fmaf(a0.y, a0.y, ss);
    ss = fmaf(a0.z, a0.z, ss);
    ss = fmaf(a0.w, a0.w, ss);
    ss = fmaf(a1.x, a1.x, ss);
    ss = fmaf(a1.y, a1.y, ss);
    ss = fmaf(a1.z, a1.z, ss);
    ss = fmaf(a1.w, a1.w, ss);
    ss = g16_reduce(ss);
    float rna = (ss > 0.f) ? rsqrtf(ss) * (1.0f / SCALE) : 0.f;
    floatx2 av0, av1, av2, av3;
    av0.x = a0.x * rna; av0.y = a0.y * rna;
    av1.x = a0.z * rna; av1.y = a0.w * rna;
    av2.x = a1.x * rna; av2.y = a1.y * rna;
    av3.x = a1.z * rna; av3.y = a1.w * rna;

    // broadcast neg indices in-register
    int js[16];
#pragma unroll
    for (int k = 0; k < 16; ++k) js[k] = __shfl(nidx, 4 * k + g, 64);

    // burst-issue all gathers; mask invalid lanes by zeroing data (fp8 0 -> 0.0f)
    uint2 vp = futq[(size_t)pidx * 16 + t];
    if (g >= P_POS) { vp.x = 0u; vp.y = 0u; }
    uint2 vs[16];
#pragma unroll
    for (int k = 0; k < 16; ++k) {
        vs[k] = futq[(size_t)js[k] * 16 + t];
        if (4 * k + g >= N_NEG) { vs[k].x = 0u; vs[k].y = 0u; }
    }

    // packed dots; two interleaved accumulators to shorten dep chains
    floatx2 na = {0.f, 0.f}, nb = {0.f, 0.f};
#pragma unroll
    for (int k = 0; k < 16; ++k) {
        uint2 v = vs[k];
        na = pkfma(__builtin_amdgcn_cvt_pk_f32_fp8(v.x, false), av0, na);
        nb = pkfma(__builtin_amdgcn_cvt_pk_f32_fp8(v.x, true), av1, nb);
        na = pkfma(__builtin_amdgcn_cvt_pk_f32_fp8(v.y, false), av2, na);
        nb = pkfma(__builtin_amdgcn_cvt_pk_f32_fp8(v.y, true), av3, nb);
    }
    floatx2 pa = {0.f, 0.f};
    pa = pkfma(__builtin_amdgcn_cvt_pk_f32_fp8(vp.x, false), av0, pa);
    pa = pkfma(__builtin_amdgcn_cvt_pk_f32_fp8(vp.x, true), av1, pa);
    pa = pkfma(__builtin_amdgcn_cvt_pk_f32_fp8(vp.y, false), av2, pa);
    pa = pkfma(__builtin_amdgcn_cvt_pk_f32_fp8(vp.y, true), av3, pa);

    float accn = wave_reduce_sum(na.x + na.y + nb.x + nb.y);
    float accp = wave_reduce_sum(pa.x + pa.y);

    if (lane == 0) {
        float sp = accp + (float)P_POS;
        float sn = accn + (float)N_NEG;
        smem[wave] = -logf(sp / (sp + sn));
    }
    __syncthreads();
    if (threadIdx.x == 0)
        atomicAdd(out, smem[0] + smem[1] + smem[2] + smem[3]);
}

extern "C" void kernel_launch(void* const* d_in, const int* in_sizes, int n_in,
                              void* d_out, int out_size, void* d_ws, size_t ws_size,
                              hipStream_t stream) {
    const float* fut  = (const float*)d_in[0];
    const float* hist = (const float*)d_in[1];
    const int* anchor_idx = (const int*)d_in[2];
    const int* pos_idx    = (const int*)d_in[3];
    const int* neg_idx    = (const int*)d_in[4];

    int N = in_sizes[0] / DIM;   // 66560
    int M = in_sizes[2];         // 16384
    int main_blocks = M / 4;     // 4096

    unsigned* futq = (unsigned*)d_ws;   // fp8 table, 128 B/row

    hipMemsetAsync(d_out, 0, sizeof(float), stream);
    int prep_blocks = (N + 7) / 8;
    prep_fp8_kernel<<<prep_blocks, 256, 0, stream>>>(fut, futq, N);
    idloss_fp8a_kernel<<<main_blocks, 256, 0, stream>>>(hist, anchor_idx, pos_idx,
                                                        neg_idx, (const uint2*)futq,
                                                        (float*)d_out);
}

// Round 11
// 31.252 us; speedup vs baseline: 2.4120x; 2.4120x over previous
//
#include <hip/hip_runtime.h>
#include <math.h>

#define DIM 128
#define P_POS 3
#define N_NEG 63
#define SCALE 16.0f

typedef float floatx2 __attribute__((ext_vector_type(2)));

#if defined(__has_builtin)
#if __has_builtin(__builtin_elementwise_fma)
#define HAVE_EFMA 1
#endif
#endif

__device__ __forceinline__ floatx2 pkfma(floatx2 a, floatx2 b, floatx2 c) {
#ifdef HAVE_EFMA
    return __builtin_elementwise_fma(a, b, c);
#else
    floatx2 r;
    r.x = fmaf(a.x, b.x, c.x);
    r.y = fmaf(a.y, b.y, c.y);
    return r;
#endif
}

__device__ __forceinline__ float wave_reduce_sum(float v) {
#pragma unroll
    for (int off = 32; off > 0; off >>= 1) v += __shfl_xor(v, off, 64);
    return v;
}
__device__ __forceinline__ float g16_reduce(float v) {
#pragma unroll
    for (int off = 8; off > 0; off >>= 1) v += __shfl_xor(v, off, 64);
    return v;
}
__device__ __forceinline__ float g32_reduce(float v) {
#pragma unroll
    for (int off = 16; off > 0; off >>= 1) v += __shfl_xor(v, off, 64);
    return v;
}

// Normalize each ids_fut row, scale by 16, pack to fp8 e4m3 (round-3 proven).
__global__ __launch_bounds__(256) void prep_fp8_kernel(const float* __restrict__ fut,
                                                       unsigned* __restrict__ futq,
                                                       int nrows) {
    int half = threadIdx.x >> 5;
    int l = threadIdx.x & 31;
    int row = blockIdx.x * 8 + half;
    if (row >= nrows) return;
    float4 x = *reinterpret_cast<const float4*>(fut + (size_t)row * DIM + l * 4);
    float ss = x.x * x.x;
    ss = fmaf(x.y, x.y, ss);
    ss = fmaf(x.z, x.z, ss);
    ss = fmaf(x.w, x.w, ss);
    ss = g32_reduce(ss);
    float r = (ss > 0.f) ? rsqrtf(ss) * SCALE : 0.f;
    int w = __builtin_amdgcn_cvt_pk_fp8_f32(x.x * r, x.y * r, 0, false);
    w = __builtin_amdgcn_cvt_pk_fp8_f32(x.z * r, x.w * r, w, true);
    futq[(size_t)row * 32 + l] = (unsigned)w;
}

// One wave per anchor; 4 groups x 16 lanes; packed-f32 dots; burst gathers.
// Round-6 proven structure; NO fences, NO atomics (r5/r10 lessons).
__global__ __launch_bounds__(256) void idloss_fp8p_kernel(
    const float* __restrict__ hist, const int* __restrict__ anchor_idx,
    const int* __restrict__ pos_idx, const int* __restrict__ neg_idx,
    const uint2* __restrict__ futq, float* __restrict__ partials) {
    __shared__ float smem[4];
    const int wave = threadIdx.x >> 6;
    const int lane = threadIdx.x & 63;
    const int m = __builtin_amdgcn_readfirstlane(blockIdx.x * 4 + wave);
    const int g = lane >> 4;
    const int t = lane & 15;

    int nidx = (lane < N_NEG) ? neg_idx[m * N_NEG + lane] : 0;

    const int aidx = anchor_idx[m];
    const int p0 = pos_idx[m * P_POS + 0];
    const int p1 = pos_idx[m * P_POS + 1];
    const int p2 = pos_idx[m * P_POS + 2];
    int pidx = (g == 1) ? p1 : (g == 2) ? p2 : p0;

    const float4* ap =
        reinterpret_cast<const float4*>(hist + (size_t)aidx * DIM + t * 8);
    float4 a0 = ap[0], a1 = ap[1];
    float ss = a0.x * a0.x;
    ss = fmaf(a0.y, a0.y, ss);
    ss = fmaf(a0.z, a0.z, ss);
    ss = fmaf(a0.w, a0.w, ss);
    ss = fmaf(a1.x, a1.x, ss);
    ss = fmaf(a1.y, a1.y, ss);
    ss = fmaf(a1.z, a1.z, ss);
    ss = fmaf(a1.w, a1.w, ss);
    ss = g16_reduce(ss);
    float rna = (ss > 0.f) ? rsqrtf(ss) * (1.0f / SCALE) : 0.f;
    floatx2 av0, av1, av2, av3;
    av0.x = a0.x * rna; av0.y = a0.y * rna;
    av1.x = a0.z * rna; av1.y = a0.w * rna;
    av2.x = a1.x * rna; av2.y = a1.y * rna;
    av3.x = a1.z * rna; av3.y = a1.w * rna;

    int js[16];
#pragma unroll
    for (int k = 0; k < 16; ++k) js[k] = __shfl(nidx, 4 * k + g, 64);

    uint2 vp = futq[(size_t)pidx * 16 + t];
    if (g >= P_POS) { vp.x = 0u; vp.y = 0u; }
    uint2 vs[16];
#pragma unroll
    for (int k = 0; k < 16; ++k) {
        vs[k] = futq[(size_t)js[k] * 16 + t];
        if (4 * k + g >= N_NEG) { vs[k].x = 0u; vs[k].y = 0u; }
    }

    floatx2 na = {0.f, 0.f}, nb = {0.f, 0.f};
#pragma unroll
    for (int k = 0; k < 16; ++k) {
        uint2 v = vs[k];
        na = pkfma(__builtin_amdgcn_cvt_pk_f32_fp8(v.x, false), av0, na);
        nb = pkfma(__builtin_amdgcn_cvt_pk_f32_fp8(v.x, true), av1, nb);
        na = pkfma(__builtin_amdgcn_cvt_pk_f32_fp8(v.y, false), av2, na);
        nb = pkfma(__builtin_amdgcn_cvt_pk_f32_fp8(v.y, true), av3, nb);
    }
    floatx2 pa = {0.f, 0.f};
    pa = pkfma(__builtin_amdgcn_cvt_pk_f32_fp8(vp.x, false), av0, pa);
    pa = pkfma(__builtin_amdgcn_cvt_pk_f32_fp8(vp.x, true), av1, pa);
    pa = pkfma(__builtin_amdgcn_cvt_pk_f32_fp8(vp.y, false), av2, pa);
    pa = pkfma(__builtin_amdgcn_cvt_pk_f32_fp8(vp.y, true), av3, pa);

    float accn = wave_reduce_sum(na.x + na.y + nb.x + nb.y);
    float accp = wave_reduce_sum(pa.x + pa.y);

    if (lane == 0) {
        float sp = accp + (float)P_POS;
        float sn = accn + (float)N_NEG;
        smem[wave] = -logf(sp / (sp + sn));
    }
    __syncthreads();
    if (threadIdx.x == 0)
        partials[blockIdx.x] = smem[0] + smem[1] + smem[2] + smem[3];
}

// Single-block 1024-thread reduce: n floats (n multiple of 4096), each thread
// owns one float4 -> one fully-parallel round trip instead of 16 serialized.
__global__ __launch_bounds__(1024) void reduce1024_kernel(
    const float* __restrict__ partials, float* __restrict__ out, int n4) {
    __shared__ float smem[16];
    const int tid = threadIdx.x;
    const int lane = tid & 63;
    const int wid = tid >> 6;
    float acc = 0.f;
    for (int i = tid; i < n4; i += 1024) {
        float4 v = reinterpret_cast<const float4*>(partials)[i];
        acc += (v.x + v.y) + (v.z + v.w);
    }
    acc = wave_reduce_sum(acc);
    if (lane == 0) smem[wid] = acc;
    __syncthreads();
    if (tid == 0) {
        float s = 0.f;
#pragma unroll
        for (int i = 0; i < 16; ++i) s += smem[i];
        out[0] = s;
    }
}

extern "C" void kernel_launch(void* const* d_in, const int* in_sizes, int n_in,
                              void* d_out, int out_size, void* d_ws, size_t ws_size,
                              hipStream_t stream) {
    const float* fut  = (const float*)d_in[0];
    const float* hist = (const float*)d_in[1];
    const int* anchor_idx = (const int*)d_in[2];
    const int* pos_idx    = (const int*)d_in[3];
    const int* neg_idx    = (const int*)d_in[4];

    int N = in_sizes[0] / DIM;   // 66560
    int M = in_sizes[2];         // 16384
    int main_blocks = M / 4;     // 4096

    size_t futq_bytes = (size_t)N * 32 * sizeof(unsigned);   // fp8 table, 128 B/row
    unsigned* futq = (unsigned*)d_ws;
    float* partials = (float*)((char*)d_ws + futq_bytes);

    int prep_blocks = (N + 7) / 8;
    prep_fp8_kernel<<<prep_blocks, 256, 0, stream>>>(fut, futq, N);
    idloss_fp8p_kernel<<<main_blocks, 256, 0, stream>>>(hist, anchor_idx, pos_idx,
                                                        neg_idx, (const uint2*)futq,
                                                        partials);
    reduce1024_kernel<<<1, 1024, 0, stream>>>(partials, (float*)d_out,
                                              main_blocks / 4);
}

// Round 12
// 31.020 us; speedup vs baseline: 2.4300x; 1.0075x over previous
//
#include <hip/hip_runtime.h>
#include <math.h>

#define DIM 128
#define P_POS 3
#define N_NEG 63
#define SCALE 16.0f

typedef float floatx2 __attribute__((ext_vector_type(2)));

#if defined(__has_builtin)
#if __has_builtin(__builtin_elementwise_fma)
#define HAVE_EFMA 1
#endif
#endif

__device__ __forceinline__ floatx2 pkfma(floatx2 a, floatx2 b, floatx2 c) {
#ifdef HAVE_EFMA
    return __builtin_elementwise_fma(a, b, c);
#else
    floatx2 r;
    r.x = fmaf(a.x, b.x, c.x);
    r.y = fmaf(a.y, b.y, c.y);
    return r;
#endif
}

__device__ __forceinline__ float wave_reduce_sum(float v) {
#pragma unroll
    for (int off = 32; off > 0; off >>= 1) v += __shfl_xor(v, off, 64);
    return v;
}
__device__ __forceinline__ float g8_reduce(float v) {
#pragma unroll
    for (int off = 4; off > 0; off >>= 1) v += __shfl_xor(v, off, 64);
    return v;
}
__device__ __forceinline__ float g32_reduce(float v) {
#pragma unroll
    for (int off = 16; off > 0; off >>= 1) v += __shfl_xor(v, off, 64);
    return v;
}

// Normalize each ids_fut row, scale by 16, pack to fp8 e4m3 (round-3 proven).
__global__ __launch_bounds__(256) void prep_fp8_kernel(const float* __restrict__ fut,
                                                       unsigned* __restrict__ futq,
                                                       int nrows) {
    int half = threadIdx.x >> 5;
    int l = threadIdx.x & 31;
    int row = blockIdx.x * 8 + half;
    if (row >= nrows) return;
    float4 x = *reinterpret_cast<const float4*>(fut + (size_t)row * DIM + l * 4);
    float ss = x.x * x.x;
    ss = fmaf(x.y, x.y, ss);
    ss = fmaf(x.z, x.z, ss);
    ss = fmaf(x.w, x.w, ss);
    ss = g32_reduce(ss);
    float r = (ss > 0.f) ? rsqrtf(ss) * SCALE : 0.f;
    int w = __builtin_amdgcn_cvt_pk_fp8_f32(x.x * r, x.y * r, 0, false);
    w = __builtin_amdgcn_cvt_pk_fp8_f32(x.z * r, x.w * r, w, true);
    futq[(size_t)row * 32 + l] = (unsigned)w;
}

// One wave per anchor; 8 groups x 8 lanes; uint4 (16 B/lane) gathers ->
// 9 gather instructions per wave (8 neg + 1 pos) instead of 17.
// r9-vs-r6 evidence: main kernel is VMEM-instruction-issue bound.
__global__ __launch_bounds__(256) void idloss_fp8w_kernel(
    const float* __restrict__ hist, const int* __restrict__ anchor_idx,
    const int* __restrict__ pos_idx, const int* __restrict__ neg_idx,
    const uint4* __restrict__ futq, float* __restrict__ partials) {
    __shared__ float smem[4];
    const int wave = threadIdx.x >> 6;
    const int lane = threadIdx.x & 63;
    const int m = __builtin_amdgcn_readfirstlane(blockIdx.x * 4 + wave);
    const int g = lane >> 3;   // group 0..7 (one sample row per group per gather)
    const int t = lane & 7;    // lane-in-group: 16 B of the 128-B row

    // per-lane coalesced neg-index load (broadcast via shfl below)
    int nidx = (lane < N_NEG) ? neg_idx[m * N_NEG + lane] : 0;

    // wave-uniform scalar loads
    const int aidx = anchor_idx[m];
    const int p0 = pos_idx[m * P_POS + 0];
    const int p1 = pos_idx[m * P_POS + 1];
    const int p2 = pos_idx[m * P_POS + 2];
    int pidx = (g == 1) ? p1 : (g == 2) ? p2 : p0;

    // anchor elements [16t, 16t+16), replicated across the 8 groups
    const float4* ap =
        reinterpret_cast<const float4*>(hist + (size_t)aidx * DIM + t * 16);
    float4 A0 = ap[0], A1 = ap[1], A2 = ap[2], A3 = ap[3];
    float ss = A0.x * A0.x;
    ss = fmaf(A0.y, A0.y, ss); ss = fmaf(A0.z, A0.z, ss); ss = fmaf(A0.w, A0.w, ss);
    ss = fmaf(A1.x, A1.x, ss); ss = fmaf(A1.y, A1.y, ss);
    ss = fmaf(A1.z, A1.z, ss); ss = fmaf(A1.w, A1.w, ss);
    ss = fmaf(A2.x, A2.x, ss); ss = fmaf(A2.y, A2.y, ss);
    ss = fmaf(A2.z, A2.z, ss); ss = fmaf(A2.w, A2.w, ss);
    ss = fmaf(A3.x, A3.x, ss); ss = fmaf(A3.y, A3.y, ss);
    ss = fmaf(A3.z, A3.z, ss); ss = fmaf(A3.w, A3.w, ss);
    ss = g8_reduce(ss);
    float rna = (ss > 0.f) ? rsqrtf(ss) * (1.0f / SCALE) : 0.f;
    floatx2 av0, av1, av2, av3, av4, av5, av6, av7;
    av0.x = A0.x * rna; av0.y = A0.y * rna;
    av1.x = A0.z * rna; av1.y = A0.w * rna;
    av2.x = A1.x * rna; av2.y = A1.y * rna;
    av3.x = A1.z * rna; av3.y = A1.w * rna;
    av4.x = A2.x * rna; av4.y = A2.y * rna;
    av5.x = A2.z * rna; av5.y = A2.w * rna;
    av6.x = A3.x * rna; av6.y = A3.y * rna;
    av7.x = A3.z * rna; av7.y = A3.w * rna;

    // broadcast neg indices in-register: gather k, group g handles slot 8k+g
    int js[8];
#pragma unroll
    for (int k = 0; k < 8; ++k) js[k] = __shfl(nidx, 8 * k + g, 64);

    // burst-issue: 1 pos gather (groups 0-2) + 8 neg gathers (slot 63 masked)
    uint4 vp = futq[(size_t)pidx * 8 + t];
    if (g >= P_POS) { vp.x = vp.y = vp.z = vp.w = 0u; }
    uint4 vs[8];
#pragma unroll
    for (int k = 0; k < 8; ++k) {
        vs[k] = futq[(size_t)js[k] * 8 + t];
        if (8 * k + g >= N_NEG) { vs[k].x = vs[k].y = vs[k].z = vs[k].w = 0u; }
    }

    // packed dots; 4 interleaved accumulators
    floatx2 n0 = {0.f, 0.f}, n1 = {0.f, 0.f}, n2 = {0.f, 0.f}, n3 = {0.f, 0.f};
#pragma unroll
    for (int k = 0; k < 8; ++k) {
        uint4 v = vs[k];
        n0 = pkfma(__builtin_amdgcn_cvt_pk_f32_fp8(v.x, false), av0, n0);
        n1 = pkfma(__builtin_amdgcn_cvt_pk_f32_fp8(v.x, true), av1, n1);
        n2 = pkfma(__builtin_amdgcn_cvt_pk_f32_fp8(v.y, false), av2, n2);
        n3 = pkfma(__builtin_amdgcn_cvt_pk_f32_fp8(v.y, true), av3, n3);
        n0 = pkfma(__builtin_amdgcn_cvt_pk_f32_fp8(v.z, false), av4, n0);
        n1 = pkfma(__builtin_amdgcn_cvt_pk_f32_fp8(v.z, true), av5, n1);
        n2 = pkfma(__builtin_amdgcn_cvt_pk_f32_fp8(v.w, false), av6, n2);
        n3 = pkfma(__builtin_amdgcn_cvt_pk_f32_fp8(v.w, true), av7, n3);
    }
    floatx2 pa = {0.f, 0.f}, pb = {0.f, 0.f};
    pa = pkfma(__builtin_amdgcn_cvt_pk_f32_fp8(vp.x, false), av0, pa);
    pb = pkfma(__builtin_amdgcn_cvt_pk_f32_fp8(vp.x, true), av1, pb);
    pa = pkfma(__builtin_amdgcn_cvt_pk_f32_fp8(vp.y, false), av2, pa);
    pb = pkfma(__builtin_amdgcn_cvt_pk_f32_fp8(vp.y, true), av3, pb);
    pa = pkfma(__builtin_amdgcn_cvt_pk_f32_fp8(vp.z, false), av4, pa);
    pb = pkfma(__builtin_amdgcn_cvt_pk_f32_fp8(vp.z, true), av5, pb);
    pa = pkfma(__builtin_amdgcn_cvt_pk_f32_fp8(vp.w, false), av6, pa);
    pb = pkfma(__builtin_amdgcn_cvt_pk_f32_fp8(vp.w, true), av7, pb);

    floatx2 ns = (n0 + n1) + (n2 + n3);
    floatx2 ps = pa + pb;
    float accn = wave_reduce_sum(ns.x + ns.y);
    float accp = wave_reduce_sum(ps.x + ps.y);

    if (lane == 0) {
        float sp = accp + (float)P_POS;
        float sn = accn + (float)N_NEG;
        smem[wave] = -logf(sp / (sp + sn));
    }
    __syncthreads();
    if (threadIdx.x == 0)
        partials[blockIdx.x] = smem[0] + smem[1] + smem[2] + smem[3];
}

// Single-block 1024-thread reduce: each thread owns one float4.
__global__ __launch_bounds__(1024) void reduce1024_kernel(
    const float* __restrict__ partials, float* __restrict__ out, int n4) {
    __shared__ float smem[16];
    const int tid = threadIdx.x;
    const int lane = tid & 63;
    const int wid = tid >> 6;
    float acc = 0.f;
    for (int i = tid; i < n4; i += 1024) {
        float4 v = reinterpret_cast<const float4*>(partials)[i];
        acc += (v.x + v.y) + (v.z + v.w);
    }
    acc = wave_reduce_sum(acc);
    if (lane == 0) smem[wid] = acc;
    __syncthreads();
    if (tid == 0) {
        float s = 0.f;
#pragma unroll
        for (int i = 0; i < 16; ++i) s += smem[i];
        out[0] = s;
    }
}

extern "C" void kernel_launch(void* const* d_in, const int* in_sizes, int n_in,
                              void* d_out, int out_size, void* d_ws, size_t ws_size,
                              hipStream_t stream) {
    const float* fut  = (const float*)d_in[0];
    const float* hist = (const float*)d_in[1];
    const int* anchor_idx = (const int*)d_in[2];
    const int* pos_idx    = (const int*)d_in[3];
    const int* neg_idx    = (const int*)d_in[4];

    int N = in_sizes[0] / DIM;   // 66560
    int M = in_sizes[2];         // 16384
    int main_blocks = M / 4;     // 4096

    size_t futq_bytes = (size_t)N * 32 * sizeof(unsigned);   // fp8 table, 128 B/row
    unsigned* futq = (unsigned*)d_ws;
    float* partials = (float*)((char*)d_ws + futq_bytes);

    int prep_blocks = (N + 7) / 8;
    prep_fp8_kernel<<<prep_blocks, 256, 0, stream>>>(fut, futq, N);
    idloss_fp8w_kernel<<<main_blocks, 256, 0, stream>>>(hist, anchor_idx, pos_idx,
                                                        neg_idx, (const uint4*)futq,
                                                        partials);
    reduce1024_kernel<<<1, 1024, 0, stream>>>(partials, (float*)d_out,
                                              main_blocks / 4);
}